// Round 18
// baseline (186.378 us; speedup 1.0000x reference)
//
#include <hip/hip_runtime.h>
#include <hip/hip_bf16.h>

#define B_ 4096
#define L_ 200
#define D_ 64
#define NJ 36
#define H1 80
#define H2 40
#define NROW (B_*L_)       // 819200 rows, row = b*200 + l
#define TPW 2              // row-tiles per wave
#define BROWS (4*16*TPW)   // 128 rows per block
#define NGRID2 (NROW/BROWS) // 6400
#define BCH 128
#define BPC (B_/BCH)       // 32
#define LJ (L_*NJ)
#define NITEM 100000
#define EPS_ 1e-8f

// k_pre block ranges
#define NCVT 3125          // NITEM*D/8 / 256
#define NTRX 128
#define NTRY 7
#define NTR (NTRX*NTRY)    // 896
// folded-K wfrag: K=192 ([h | it | h*it] with Wa+Wc, Wb-Wc, Wd). 6 K-steps.
#define WF_SZ 6912         // 6144 (tiles 0,1) + 768 (tile2 compact) ush = 864 float4
#define NPREP (WF_SZ/256)  // 27
#define NPRE (NCVT+NTR+NPREP+1)

typedef short bf16x8 __attribute__((ext_vector_type(8)));
typedef float f32x4 __attribute__((ext_vector_type(4)));
typedef unsigned short u16x8 __attribute__((ext_vector_type(8)));
typedef unsigned short u16x4 __attribute__((ext_vector_type(4)));

__device__ __forceinline__ float sigmoidf_(float x) { return 1.0f / (1.0f + __expf(-x)); }

__device__ __forceinline__ unsigned short bfr(float x) {   // f32 -> bf16 RNE
    unsigned u = __float_as_uint(x);
    return (unsigned short)((u + 0x7fffu + ((u >> 16) & 1u)) >> 16);
}
__device__ __forceinline__ float bf2f(unsigned short v) {
    return __uint_as_float(((unsigned)v) << 16);
}
__device__ __forceinline__ unsigned cvtpk(float lo, float hi) {
    unsigned r;
    asm("v_cvt_pk_bf16_f32 %0, %1, %2" : "=v"(r) : "v"(lo), "v"(hi));
    return r;
}
__device__ __forceinline__ u16x8 pk8u(float4 a, float4 b) {
    union { unsigned u[4]; u16x8 v; } r;
    r.u[0] = cvtpk(a.x, a.y); r.u[1] = cvtpk(a.z, a.w);
    r.u[2] = cvtpk(b.x, b.y); r.u[3] = cvtpk(b.z, b.w);
    return r.v;
}
__device__ __forceinline__ bf16x8 asbf(u16x8 v) {
    union { u16x8 u; bf16x8 b; } c; c.u = v; return c.b;
}
__device__ __forceinline__ bf16x8 bmul8(u16x8 a, u16x8 b) {
    union { unsigned u[4]; bf16x8 v; } r;
    #pragma unroll
    for (int i = 0; i < 4; ++i)
        r.u[i] = cvtpk(bf2f(a[2*i]) * bf2f(b[2*i]), bf2f(a[2*i+1]) * bf2f(b[2*i+1]));
    return r.v;
}

// K_PRE: fused preamble — [cvt i_emb->bf16 | transpose hist | folded wfrag prep | coef+zero]
__global__ __launch_bounds__(256) void k_pre(const float* __restrict__ i_emb,
        unsigned short* __restrict__ iemb16, const int* __restrict__ hist,
        int* __restrict__ histT, const float* __restrict__ auW1,
        unsigned short* __restrict__ wfrag, const float* __restrict__ alpha,
        const float* __restrict__ auW2, float* __restrict__ c01, float* __restrict__ gzero) {
    __shared__ int tile[32][33];
    int bid = blockIdx.x, tid = threadIdx.x;
    if (bid < NCVT) {
        int g = bid * 256 + tid;                     // < 800000 exact
        const float4* s4 = (const float4*)i_emb;
        float4 a = s4[g * 2], b = s4[g * 2 + 1];
        ((u16x8*)iemb16)[g] = pk8u(a, b);
    } else if (bid < NCVT + NTR) {
        int t = bid - NCVT;
        int b0 = (t % NTRX) * 32, l0 = (t / NTRX) * 32;
        int tx = tid & 31, ty = tid >> 5;            // 32 x 8
        #pragma unroll
        for (int i = 0; i < 4; ++i) {
            int l = l0 + ty + i * 8;
            if (l < L_) tile[ty + i * 8][tx] = hist[l * B_ + b0 + tx];
        }
        __syncthreads();
        #pragma unroll
        for (int i = 0; i < 4; ++i) {
            int b = b0 + ty + i * 8;
            int l = l0 + tx;
            if (l < L_) histT[b * L_ + l] = tile[tx][ty + i * 8];
        }
    } else if (bid < NCVT + NTR + NPREP) {
        int s = (bid - (NCVT + NTR)) * 256 + tid;    // < 6912
        int k, n;
        if (s < 6144) {                               // tiles 0,1 (n = 0..31)
            int t = s >> 3;
            int e = s & 7, lane = t & 63;
            int g = t >> 6;
            int ks = g % 6, nt = g / 6;
            n = nt * 16 + (lane & 15);
            k = ks * 32 + ((lane >> 4) << 3) + e;
        } else {                                      // tile 2 compact (n = 32..35)
            int t2 = s - 6144;
            int e = t2 & 7, slot = (t2 >> 3) & 15, ks = t2 >> 7;
            n = 32 + (slot & 3);
            k = ks * 32 + (slot >> 2) * 8 + e;
        }
        // folded weights: seg0: Wa+Wc, seg1: Wb-Wc, seg2: Wd
        int d = k & 63, seg = k >> 6;
        float w;
        if (seg == 0)      w = auW1[d * NJ + n] + auW1[(128 + d) * NJ + n];
        else if (seg == 1) w = auW1[(64 + d) * NJ + n] - auW1[(128 + d) * NJ + n];
        else               w = auW1[(192 + d) * NJ + n];
        wfrag[s] = bfr(w);
    } else {
        if (tid < NJ) {
            float a = alpha[tid], w = auW2[tid];
            c01[2 * tid] = w * a;
            c01[2 * tid + 1] = w * (1.f - a);
        }
        if (tid < 2 * H1 + 2 * H2) gzero[tid] = 0.f;   // all 240 accumulator floats
    }
}

// K1: A[row][j] = bf16( h·(Wa+Wc) + it·(Wb-Wc) + (h∘it)·Wd + b1 ), K=192 folded.
//     (256,4): (256,6) forced VGPR=40 and spilled ~140 MB to scratch (round 11).
__global__ __launch_bounds__(256, 4) void k_gemm(const int* __restrict__ histT,
        const int* __restrict__ item, const unsigned short* __restrict__ i_emb16,
        const unsigned short* __restrict__ wfrag, const float* __restrict__ aub1,
        unsigned short* __restrict__ A16) {
    __shared__ __align__(16) unsigned short wls[WF_SZ + 16];   // 13.9 KB
    int tid = threadIdx.x;
    int wv = tid >> 6, lane = tid & 63;
    int m = lane & 15, kg = lane >> 4;

    int wt0 = (blockIdx.x * 4 + wv) * TPW;
    int g0 = wt0 * 16 + m;
    int g1 = g0 + 16;
    int b0 = g0 / L_, l0 = g0 - b0 * L_;
    int b1 = g1 / L_, l1 = g1 - b1 * L_;
    int h0 = histT[b0 * L_ + l0];
    int i0 = item[b0];
    int h1 = histT[b1 * L_ + l1];
    int i1 = item[b1];

    {   // stage 864 float4 (6912 ush / 8 per float4) + zero slot
        const float4* src = (const float4*)wfrag;
        float4* dst = (float4*)wls;
        #pragma unroll
        for (int i = 0; i < 3; ++i) dst[i * 256 + tid] = src[i * 256 + tid];
        if (tid < 96) dst[768 + tid] = src[768 + tid];
        if (tid == 100) *(float4*)(wls + WF_SZ) = make_float4(0.f, 0.f, 0.f, 0.f);
        if (tid == 101) *(float4*)(wls + WF_SZ + 8) = make_float4(0.f, 0.f, 0.f, 0.f);
    }

    const u16x8* hp0 = (const u16x8*)(i_emb16 + (long)h0 * D_);
    const u16x8* ip0 = (const u16x8*)(i_emb16 + (long)i0 * D_);
    const u16x8* hp1 = (const u16x8*)(i_emb16 + (long)h1 * D_);
    const u16x8* ip1 = (const u16x8*)(i_emb16 + (long)i1 * D_);
    u16x8 ha = hp0[kg], hb = hp0[4 + kg];
    u16x8 ta = ip0[kg], tb = ip0[4 + kg];
    u16x8 ea = hp1[kg], eb = hp1[4 + kg];
    u16x8 ua = ip1[kg], ub = ip1[4 + kg];

    bf16x8 af0[6], af1[6];
    af0[0] = asbf(ha); af0[1] = asbf(hb);
    af0[2] = asbf(ta); af0[3] = asbf(tb);
    af0[4] = bmul8(ha, ta); af0[5] = bmul8(hb, tb);
    af1[0] = asbf(ea); af1[1] = asbf(eb);
    af1[2] = asbf(ua); af1[3] = asbf(ub);
    af1[4] = bmul8(ea, ua); af1[5] = bmul8(eb, ub);

    __syncthreads();

    const bf16x8* wf = (const bf16x8*)wls;
    bool v2 = (m < 4);
    int base2 = (kg * 4 + m) * 8;                  // tile2 compact offset (valid lanes)
    f32x4 c00 = {0.f,0.f,0.f,0.f}, c01v = c00, c02 = c00;
    f32x4 c10 = c00, c11 = c00, c12 = c00;
    #pragma unroll
    for (int ks = 0; ks < 6; ++ks) {
        bf16x8 w0 = wf[ks * 64 + lane];
        bf16x8 w1 = wf[(6 + ks) * 64 + lane];
        int o2 = v2 ? (6144 + ks * 128 + base2) : WF_SZ;
        bf16x8 w2 = *(const bf16x8*)(wls + o2);
        c00 = __builtin_amdgcn_mfma_f32_16x16x32_bf16(af0[ks], w0, c00, 0, 0, 0);
        c10 = __builtin_amdgcn_mfma_f32_16x16x32_bf16(af1[ks], w0, c10, 0, 0, 0);
        c01v = __builtin_amdgcn_mfma_f32_16x16x32_bf16(af0[ks], w1, c01v, 0, 0, 0);
        c11 = __builtin_amdgcn_mfma_f32_16x16x32_bf16(af1[ks], w1, c11, 0, 0, 0);
        c02 = __builtin_amdgcn_mfma_f32_16x16x32_bf16(af0[ks], w2, c02, 0, 0, 0);
        c12 = __builtin_amdgcn_mfma_f32_16x16x32_bf16(af1[ks], w2, c12, 0, 0, 0);
    }

    float bias0 = aub1[m], bias1 = aub1[16 + m];
    float bias2 = v2 ? aub1[32 + m] : 0.f;
    long rb0 = (long)wt0 * 16 + kg * 4;
    #pragma unroll
    for (int i = 0; i < 4; ++i) {
        unsigned short* o = A16 + (rb0 + i) * NJ;
        o[m]      = bfr(c00[i] + bias0);
        o[16 + m] = bfr(c01v[i] + bias1);
        if (v2) o[32 + m] = bfr(c02[i] + bias2);
    }
    long rb1 = rb0 + 16;
    #pragma unroll
    for (int i = 0; i < 4; ++i) {
        unsigned short* o = A16 + (rb1 + i) * NJ;
        o[m]      = bfr(c10[i] + bias0);
        o[16 + m] = bfr(c11[i] + bias1);
        if (v2) o[32 + m] = bfr(c12[i] + bias2);
    }
}

// K1b: partial stats, short8 loads (BCH=128 -> 512 blocks; 256 was a regression, round 13)
__global__ __launch_bounds__(256) void k_stats_p(const unsigned short* __restrict__ A16,
        float* __restrict__ sp, float* __restrict__ sq) {
    int t = blockIdx.x * 256 + threadIdx.x;
    if (t >= LJ / 8) return;   // 900
    int c = blockIdx.y;
    const u16x8* base = (const u16x8*)(A16 + (long)c * BPC * LJ) + t;
    float s[8], q[8];
    #pragma unroll
    for (int i = 0; i < 8; ++i) { s[i] = 0.f; q[i] = 0.f; }
    #pragma unroll 4
    for (int b = 0; b < BPC; ++b) {
        u16x8 v = base[(long)b * (LJ / 8)];
        #pragma unroll
        for (int i = 0; i < 8; ++i) {
            float f = bf2f(v[i]);
            s[i] += f; q[i] += f * f;
        }
    }
    #pragma unroll
    for (int i = 0; i < 8; ++i) {
        sp[(long)c * LJ + t * 8 + i] = s[i];
        sq[(long)c * LJ + t * 8 + i] = q[i];
    }
}

// K1c: finish stats -> packed bf16 {mean, rstd} per lj
__global__ void k_stats_fin(const float* __restrict__ sp, const float* __restrict__ sq,
                            unsigned* __restrict__ mr16) {
    int lj = blockIdx.x * 256 + threadIdx.x;
    if (lj >= LJ) return;
    float s = 0.f, q = 0.f;
    for (int c = 0; c < BCH; ++c) { s += sp[(long)c * LJ + lj]; q += sq[(long)c * LJ + lj]; }
    float m = s * (1.0f / B_);
    float v = fmaxf(q * (1.0f / B_) - m * m, 0.f);
    mr16[lj] = cvtpk(m, rsqrtf(v + EPS_));   // lo = mean, hi = rstd
}

// K2: fused dice-weight + pooling. One block = 2 batch rows; A16 LDS-staged;
//     cur[b][d] = sum_l w[b][l]*h[b][l][d]; z = [u|it|c|cur].
__global__ __launch_bounds__(256) void k_wp(const unsigned short* __restrict__ A16,
        const unsigned* __restrict__ mr16, const float* __restrict__ c01,
        const float* __restrict__ aub2, const int* __restrict__ histT,
        const int* __restrict__ user, const int* __restrict__ item, const int* __restrict__ cate,
        const float* __restrict__ u_emb, const float* __restrict__ i_emb, const float* __restrict__ c_emb,
        const unsigned short* __restrict__ i_emb16, float* __restrict__ z_buf) {
    __shared__ __align__(16) unsigned short aL[2 * L_ * NJ];   // 28.8 KB = 1800 u16x8
    __shared__ float wl[2 * L_];
    __shared__ float part[2][2][D_];
    int tid = threadIdx.x;
    int b0 = blockIdx.x * 2;
    {   // stage 400 rows of A16: 1800 u16x8, coalesced (8 sweeps, guarded)
        const u16x8* gsrc = (const u16x8*)(A16 + (long)b0 * L_ * NJ);
        u16x8* ld = (u16x8*)aL;
        #pragma unroll
        for (int i = 0; i < 8; ++i) {
            int idx = i * 256 + tid;
            if (idx < 1800) ld[idx] = gsrc[idx];
        }
    }
    __syncthreads();
    float base_w = aub2[0];
    for (int r = tid; r < 2 * L_; r += 256) {
        int l = (r >= L_) ? r - L_ : r;
        const u16x4* Ab4 = (const u16x4*)(aL + r * NJ);
        const u16x8* mrp = (const u16x8*)(mr16 + l * NJ);
        float w = base_w;
        #pragma unroll
        for (int cgi = 0; cgi < 9; ++cgi) {
            u16x4 av = Ab4[cgi];
            u16x8 mr = mrp[cgi];
            #pragma unroll
            for (int i = 0; i < 4; ++i) {
                int j = cgi * 4 + i;
                float s = bf2f(av[i]);
                float p = sigmoidf_((s - bf2f(mr[2 * i])) * bf2f(mr[2 * i + 1]));
                w += s * fmaf(c01[2 * j + 1], p, c01[2 * j]);
            }
        }
        wl[r] = w;
    }
    __syncthreads();
    {   // pool: wave-uniform (bs, half) per wave64 -> histT reads are s_loads
        int bs = tid >> 7, half = (tid >> 6) & 1, d = tid & 63;
        int b = b0 + bs;
        const int* rp = histT + b * L_;
        const float* wp = wl + bs * L_;
        float s = 0.f;
        int l0 = half * 100;
        #pragma unroll 4
        for (int i = 0; i < 100; ++i) {
            int ll = l0 + i;
            s += wp[ll] * bf2f(i_emb16[(long)rp[ll] * D_ + d]);
        }
        part[bs][half][d] = s;
    }
    __syncthreads();
    for (int o = tid; o < 512; o += 256) {
        int bs = o >> 8, idx = o & 255, seg = idx >> 6, d = idx & 63;
        int b = b0 + bs;
        float v;
        if (seg == 0)      v = u_emb[(long)user[b] * D_ + d];
        else if (seg == 1) v = i_emb[(long)item[b] * D_ + d];
        else if (seg == 2) v = c_emb[(long)cate[b] * D_ + d];
        else               v = part[bs][0][d] + part[bs][1][d];
        z_buf[b * 256 + idx] = v;
    }
}

// K4: y1 = z @ W1 + b1 (+ batch stats)
__global__ __launch_bounds__(256) void k_mlp1(const float* __restrict__ z_buf,
        const float* __restrict__ W1, const float* __restrict__ b1,
        float* __restrict__ y1, float* __restrict__ gs1, float* __restrict__ gq1) {
    __shared__ float zt[16 * 256];
    __shared__ float w_s[256 * H1];
    __shared__ float ls[H1], lq[H1];
    int tid = threadIdx.x;
    int b0 = blockIdx.x * 16;
    for (int i = tid; i < 16 * 256; i += 256) zt[i] = z_buf[b0 * 256 + i];
    for (int i = tid; i < 256 * H1; i += 256) w_s[i] = W1[i];
    if (tid < H1) { ls[tid] = 0.f; lq[tid] = 0.f; }
    __syncthreads();
    for (int o = tid; o < 16 * H1; o += 256) {
        int bl = o / H1, j = o - bl * H1;
        float s = b1[j];
        for (int k = 0; k < 256; ++k) s += zt[bl * 256 + k] * w_s[k * H1 + j];
        y1[(b0 + bl) * H1 + j] = s;
        atomicAdd(&ls[j], s); atomicAdd(&lq[j], s * s);
    }
    __syncthreads();
    if (tid < H1) { atomicAdd(&gs1[tid], ls[tid]); atomicAdd(&gq1[tid], lq[tid]); }
}

// K6: a1 = dice1(y1); y2 = a1 @ W2 + b2 (+ stats). m1/r1 computed per-block from gs1/gq1
__global__ __launch_bounds__(256) void k_mlp2(const float* __restrict__ y1,
        const float* __restrict__ gs1, const float* __restrict__ gq1, const float* __restrict__ alpha1,
        const float* __restrict__ W2, const float* __restrict__ b2,
        float* __restrict__ y2, float* __restrict__ gs2, float* __restrict__ gq2) {
    __shared__ float at[16 * H1];
    __shared__ float w_s[H1 * H2];
    __shared__ float ls[H2], lq[H2];
    __shared__ float m1s[H1], r1s[H1];
    int tid = threadIdx.x;
    int b0 = blockIdx.x * 16;
    if (tid < H1) {
        float mm = gs1[tid] * (1.0f / B_);
        float v = fmaxf(gq1[tid] * (1.0f / B_) - mm * mm, 0.f);
        m1s[tid] = mm; r1s[tid] = rsqrtf(v + EPS_);
    }
    for (int i = tid; i < H1 * H2; i += 256) w_s[i] = W2[i];
    if (tid < H2) { ls[tid] = 0.f; lq[tid] = 0.f; }
    __syncthreads();
    for (int i = tid; i < 16 * H1; i += 256) {
        float x = y1[b0 * H1 + i];
        int j = i % H1;
        float p = sigmoidf_((x - m1s[j]) * r1s[j]);
        at[i] = x * (p + alpha1[j] * (1.f - p));
    }
    __syncthreads();
    for (int o = tid; o < 16 * H2; o += 256) {
        int bl = o / H2, j = o - bl * H2;
        float s = b2[j];
        #pragma unroll
        for (int k = 0; k < H1; ++k) s += at[bl * H1 + k] * w_s[k * H2 + j];
        y2[(b0 + bl) * H2 + j] = s;
        atomicAdd(&ls[j], s); atomicAdd(&lq[j], s * s);
    }
    __syncthreads();
    if (tid < H2) { atomicAdd(&gs2[tid], ls[tid]); atomicAdd(&gq2[tid], lq[tid]); }
}

// K8: out = dice2(y2) @ W3 + b3. m2/r2 computed per-block from gs2/gq2
__global__ __launch_bounds__(256) void k_out(const float* __restrict__ y2,
        const float* __restrict__ gs2, const float* __restrict__ gq2, const float* __restrict__ alpha2,
        const float* __restrict__ W3, const float* __restrict__ b3, float* __restrict__ out) {
    __shared__ float m2s[H2], r2s[H2];
    int tid = threadIdx.x;
    if (tid < H2) {
        float mm = gs2[tid] * (1.0f / B_);
        float v = fmaxf(gq2[tid] * (1.0f / B_) - mm * mm, 0.f);
        m2s[tid] = mm; r2s[tid] = rsqrtf(v + EPS_);
    }
    __syncthreads();
    int b = blockIdx.x * 256 + tid;
    if (b >= B_) return;
    float s0 = b3[0], s1 = b3[1];
    #pragma unroll
    for (int k = 0; k < H2; ++k) {
        float x = y2[b * H2 + k];
        float p = sigmoidf_((x - m2s[k]) * r2s[k]);
        float a = x * (p + alpha2[k] * (1.f - p));
        s0 += a * W3[k * 2];
        s1 += a * W3[k * 2 + 1];
    }
    out[b * 2] = s0;
    out[b * 2 + 1] = s1;
}

extern "C" void kernel_launch(void* const* d_in, const int* in_sizes, int n_in,
                              void* d_out, int out_size, void* d_ws, size_t ws_size,
                              hipStream_t stream) {
    const int*   user  = (const int*)d_in[0];
    const int*   hist  = (const int*)d_in[1];
    const int*   item  = (const int*)d_in[2];
    const int*   cate  = (const int*)d_in[3];
    const float* u_emb = (const float*)d_in[4];
    const float* i_emb = (const float*)d_in[5];
    const float* c_emb = (const float*)d_in[6];
    const float* auW1  = (const float*)d_in[7];
    const float* aub1  = (const float*)d_in[8];
    const float* aual  = (const float*)d_in[9];
    const float* auW2  = (const float*)d_in[10];
    const float* aub2  = (const float*)d_in[11];
    const float* W1    = (const float*)d_in[12];
    const float* b1    = (const float*)d_in[13];
    const float* al1   = (const float*)d_in[14];
    const float* W2    = (const float*)d_in[15];
    const float* b2    = (const float*)d_in[16];
    const float* al2   = (const float*)d_in[17];
    const float* W3    = (const float*)d_in[18];
    const float* b3    = (const float*)d_in[19];

    unsigned short* A16    = (unsigned short*)d_ws;            // 59 MB bf16
    unsigned short* wfrag  = A16 + (size_t)NROW * NJ;          // 13.8 KB
    unsigned short* iemb16 = wfrag + WF_SZ;                    // 12.8 MB
    float* ws = (float*)(iemb16 + (size_t)NITEM * D_);
    size_t off = 0;
    float* sp    = ws + off; off += (size_t)BCH * LJ;          // 3.7 MB
    float* sq    = ws + off; off += (size_t)BCH * LJ;          // 3.7 MB
    unsigned* mr16 = (unsigned*)(ws + off); off += LJ;         // 28.8 KB packed {m,r}
    float* c01   = ws + off; off += 2 * NJ;
    float* gs1   = ws + off; off += H1;
    float* gq1   = ws + off; off += H1;
    float* gs2   = ws + off; off += H2;
    float* gq2   = ws + off; off += H2;
    float* z_buf = ws + off; off += (size_t)B_ * 256;
    float* y1    = ws + off; off += (size_t)B_ * H1;
    float* y2    = ws + off; off += (size_t)B_ * H2;
    int* histT   = (int*)(ws + off); off += NROW;              // 3.3 MB

    k_pre<<<NPRE, 256, 0, stream>>>(i_emb, iemb16, hist, histT, auW1, wfrag,
                                    aual, auW2, c01, gs1);
    k_gemm<<<NGRID2, 256, 0, stream>>>(histT, item, iemb16, wfrag, aub1, A16);
    {
        dim3 g(4, BCH);
        k_stats_p<<<g, 256, 0, stream>>>(A16, sp, sq);
    }
    k_stats_fin<<<(LJ + 255) / 256, 256, 0, stream>>>(sp, sq, mr16);
    k_wp<<<B_ / 2, 256, 0, stream>>>(A16, mr16, c01, aub2, histT, user, item, cate,
                                     u_emb, i_emb, c_emb, iemb16, z_buf);
    k_mlp1<<<B_ / 16, 256, 0, stream>>>(z_buf, W1, b1, y1, gs1, gq1);
    k_mlp2<<<B_ / 16, 256, 0, stream>>>(y1, gs1, gq1, al1, W2, b2, y2, gs2, gq2);
    k_out<<<B_ / 256, 256, 0, stream>>>(y2, gs2, gq2, al2, W3, b3, (float*)d_out);
}

// Round 19
// 168.742 us; speedup vs baseline: 1.1045x; 1.1045x over previous
//
#include <hip/hip_runtime.h>
#include <hip/hip_bf16.h>

#define B_ 4096
#define L_ 200
#define D_ 64
#define NJ 36
#define H1 80
#define H2 40
#define NROW (B_*L_)       // 819200 rows, row = b*200 + l
#define TPW 2              // row-tiles per wave
#define BROWS (4*16*TPW)   // 128 rows per block
#define NGRID2 (NROW/BROWS) // 6400
#define BCH 128
#define BPC (B_/BCH)       // 32
#define LJ (L_*NJ)
#define NITEM 100000
#define EPS_ 1e-8f

// k_pre block ranges
#define NCVT 3125          // NITEM*D/8 / 256
#define NTRX 128
#define NTRY 7
#define NTR (NTRX*NTRY)    // 896
// folded-K wfrag: K=192 ([h | it | h*it] with Wa+Wc, Wb-Wc, Wd). 6 K-steps.
#define WF_SZ 6912         // 6144 (tiles 0,1) + 768 (tile2 compact) ush = 864 float4
#define NPREP (WF_SZ/256)  // 27
#define NPRE (NCVT+NTR+NPREP+1)

typedef short bf16x8 __attribute__((ext_vector_type(8)));
typedef float f32x4 __attribute__((ext_vector_type(4)));
typedef unsigned short u16x8 __attribute__((ext_vector_type(8)));
typedef unsigned short u16x4 __attribute__((ext_vector_type(4)));

__device__ __forceinline__ float sigmoidf_(float x) { return 1.0f / (1.0f + __expf(-x)); }

__device__ __forceinline__ unsigned short bfr(float x) {   // f32 -> bf16 RNE
    unsigned u = __float_as_uint(x);
    return (unsigned short)((u + 0x7fffu + ((u >> 16) & 1u)) >> 16);
}
__device__ __forceinline__ float bf2f(unsigned short v) {
    return __uint_as_float(((unsigned)v) << 16);
}
__device__ __forceinline__ unsigned cvtpk(float lo, float hi) {
    unsigned r;
    asm("v_cvt_pk_bf16_f32 %0, %1, %2" : "=v"(r) : "v"(lo), "v"(hi));
    return r;
}
__device__ __forceinline__ u16x8 pk8u(float4 a, float4 b) {
    union { unsigned u[4]; u16x8 v; } r;
    r.u[0] = cvtpk(a.x, a.y); r.u[1] = cvtpk(a.z, a.w);
    r.u[2] = cvtpk(b.x, b.y); r.u[3] = cvtpk(b.z, b.w);
    return r.v;
}
__device__ __forceinline__ bf16x8 asbf(u16x8 v) {
    union { u16x8 u; bf16x8 b; } c; c.u = v; return c.b;
}
__device__ __forceinline__ bf16x8 bmul8(u16x8 a, u16x8 b) {
    union { unsigned u[4]; bf16x8 v; } r;
    #pragma unroll
    for (int i = 0; i < 4; ++i)
        r.u[i] = cvtpk(bf2f(a[2*i]) * bf2f(b[2*i]), bf2f(a[2*i+1]) * bf2f(b[2*i+1]));
    return r.v;
}

// K_PRE: fused preamble — [cvt i_emb->bf16 | transpose hist | folded wfrag prep | coef+zero]
__global__ __launch_bounds__(256) void k_pre(const float* __restrict__ i_emb,
        unsigned short* __restrict__ iemb16, const int* __restrict__ hist,
        int* __restrict__ histT, const float* __restrict__ auW1,
        unsigned short* __restrict__ wfrag, const float* __restrict__ alpha,
        const float* __restrict__ auW2, float* __restrict__ c01, float* __restrict__ gzero) {
    __shared__ int tile[32][33];
    int bid = blockIdx.x, tid = threadIdx.x;
    if (bid < NCVT) {
        int g = bid * 256 + tid;                     // < 800000 exact
        const float4* s4 = (const float4*)i_emb;
        float4 a = s4[g * 2], b = s4[g * 2 + 1];
        ((u16x8*)iemb16)[g] = pk8u(a, b);
    } else if (bid < NCVT + NTR) {
        int t = bid - NCVT;
        int b0 = (t % NTRX) * 32, l0 = (t / NTRX) * 32;
        int tx = tid & 31, ty = tid >> 5;            // 32 x 8
        #pragma unroll
        for (int i = 0; i < 4; ++i) {
            int l = l0 + ty + i * 8;
            if (l < L_) tile[ty + i * 8][tx] = hist[l * B_ + b0 + tx];
        }
        __syncthreads();
        #pragma unroll
        for (int i = 0; i < 4; ++i) {
            int b = b0 + ty + i * 8;
            int l = l0 + tx;
            if (l < L_) histT[b * L_ + l] = tile[tx][ty + i * 8];
        }
    } else if (bid < NCVT + NTR + NPREP) {
        int s = (bid - (NCVT + NTR)) * 256 + tid;    // < 6912
        int k, n;
        if (s < 6144) {                               // tiles 0,1 (n = 0..31)
            int t = s >> 3;
            int e = s & 7, lane = t & 63;
            int g = t >> 6;
            int ks = g % 6, nt = g / 6;
            n = nt * 16 + (lane & 15);
            k = ks * 32 + ((lane >> 4) << 3) + e;
        } else {                                      // tile 2 compact (n = 32..35)
            int t2 = s - 6144;
            int e = t2 & 7, slot = (t2 >> 3) & 15, ks = t2 >> 7;
            n = 32 + (slot & 3);
            k = ks * 32 + (slot >> 2) * 8 + e;
        }
        // folded weights: seg0: Wa+Wc, seg1: Wb-Wc, seg2: Wd
        int d = k & 63, seg = k >> 6;
        float w;
        if (seg == 0)      w = auW1[d * NJ + n] + auW1[(128 + d) * NJ + n];
        else if (seg == 1) w = auW1[(64 + d) * NJ + n] - auW1[(128 + d) * NJ + n];
        else               w = auW1[(192 + d) * NJ + n];
        wfrag[s] = bfr(w);
    } else {
        if (tid < NJ) {
            float a = alpha[tid], w = auW2[tid];
            c01[2 * tid] = w * a;
            c01[2 * tid + 1] = w * (1.f - a);
        }
        if (tid < 2 * H1 + 2 * H2) gzero[tid] = 0.f;   // all 240 accumulator floats
    }
}

// K1: A[row][j] = bf16( h·(Wa+Wc) + it·(Wb-Wc) + (h∘it)·Wd + b1 ), K=192 folded.
//     (256,4): (256,6) forced VGPR=40 and spilled ~140 MB to scratch (round 11).
__global__ __launch_bounds__(256, 4) void k_gemm(const int* __restrict__ histT,
        const int* __restrict__ item, const unsigned short* __restrict__ i_emb16,
        const unsigned short* __restrict__ wfrag, const float* __restrict__ aub1,
        unsigned short* __restrict__ A16) {
    __shared__ __align__(16) unsigned short wls[WF_SZ + 16];   // 13.9 KB
    int tid = threadIdx.x;
    int wv = tid >> 6, lane = tid & 63;
    int m = lane & 15, kg = lane >> 4;

    int wt0 = (blockIdx.x * 4 + wv) * TPW;
    int g0 = wt0 * 16 + m;
    int g1 = g0 + 16;
    int b0 = g0 / L_, l0 = g0 - b0 * L_;
    int b1 = g1 / L_, l1 = g1 - b1 * L_;
    int h0 = histT[b0 * L_ + l0];
    int i0 = item[b0];
    int h1 = histT[b1 * L_ + l1];
    int i1 = item[b1];

    {   // stage 864 float4 (6912 ush / 8 per float4) + zero slot
        const float4* src = (const float4*)wfrag;
        float4* dst = (float4*)wls;
        #pragma unroll
        for (int i = 0; i < 3; ++i) dst[i * 256 + tid] = src[i * 256 + tid];
        if (tid < 96) dst[768 + tid] = src[768 + tid];
        if (tid == 100) *(float4*)(wls + WF_SZ) = make_float4(0.f, 0.f, 0.f, 0.f);
        if (tid == 101) *(float4*)(wls + WF_SZ + 8) = make_float4(0.f, 0.f, 0.f, 0.f);
    }

    const u16x8* hp0 = (const u16x8*)(i_emb16 + (long)h0 * D_);
    const u16x8* ip0 = (const u16x8*)(i_emb16 + (long)i0 * D_);
    const u16x8* hp1 = (const u16x8*)(i_emb16 + (long)h1 * D_);
    const u16x8* ip1 = (const u16x8*)(i_emb16 + (long)i1 * D_);
    u16x8 ha = hp0[kg], hb = hp0[4 + kg];
    u16x8 ta = ip0[kg], tb = ip0[4 + kg];
    u16x8 ea = hp1[kg], eb = hp1[4 + kg];
    u16x8 ua = ip1[kg], ub = ip1[4 + kg];

    bf16x8 af0[6], af1[6];
    af0[0] = asbf(ha); af0[1] = asbf(hb);
    af0[2] = asbf(ta); af0[3] = asbf(tb);
    af0[4] = bmul8(ha, ta); af0[5] = bmul8(hb, tb);
    af1[0] = asbf(ea); af1[1] = asbf(eb);
    af1[2] = asbf(ua); af1[3] = asbf(ub);
    af1[4] = bmul8(ea, ua); af1[5] = bmul8(eb, ub);

    __syncthreads();

    const bf16x8* wf = (const bf16x8*)wls;
    bool v2 = (m < 4);
    int base2 = (kg * 4 + m) * 8;                  // tile2 compact offset (valid lanes)
    f32x4 c00 = {0.f,0.f,0.f,0.f}, c01v = c00, c02 = c00;
    f32x4 c10 = c00, c11 = c00, c12 = c00;
    #pragma unroll
    for (int ks = 0; ks < 6; ++ks) {
        bf16x8 w0 = wf[ks * 64 + lane];
        bf16x8 w1 = wf[(6 + ks) * 64 + lane];
        int o2 = v2 ? (6144 + ks * 128 + base2) : WF_SZ;
        bf16x8 w2 = *(const bf16x8*)(wls + o2);
        c00 = __builtin_amdgcn_mfma_f32_16x16x32_bf16(af0[ks], w0, c00, 0, 0, 0);
        c10 = __builtin_amdgcn_mfma_f32_16x16x32_bf16(af1[ks], w0, c10, 0, 0, 0);
        c01v = __builtin_amdgcn_mfma_f32_16x16x32_bf16(af0[ks], w1, c01v, 0, 0, 0);
        c11 = __builtin_amdgcn_mfma_f32_16x16x32_bf16(af1[ks], w1, c11, 0, 0, 0);
        c02 = __builtin_amdgcn_mfma_f32_16x16x32_bf16(af0[ks], w2, c02, 0, 0, 0);
        c12 = __builtin_amdgcn_mfma_f32_16x16x32_bf16(af1[ks], w2, c12, 0, 0, 0);
    }

    float bias0 = aub1[m], bias1 = aub1[16 + m];
    float bias2 = v2 ? aub1[32 + m] : 0.f;
    long rb0 = (long)wt0 * 16 + kg * 4;
    #pragma unroll
    for (int i = 0; i < 4; ++i) {
        unsigned short* o = A16 + (rb0 + i) * NJ;
        o[m]      = bfr(c00[i] + bias0);
        o[16 + m] = bfr(c01v[i] + bias1);
        if (v2) o[32 + m] = bfr(c02[i] + bias2);
    }
    long rb1 = rb0 + 16;
    #pragma unroll
    for (int i = 0; i < 4; ++i) {
        unsigned short* o = A16 + (rb1 + i) * NJ;
        o[m]      = bfr(c10[i] + bias0);
        o[16 + m] = bfr(c11[i] + bias1);
        if (v2) o[32 + m] = bfr(c12[i] + bias2);
    }
}

// K1b: partial stats, short8 loads (BCH=128 -> 512 blocks; 256 was a regression, round 13)
__global__ __launch_bounds__(256) void k_stats_p(const unsigned short* __restrict__ A16,
        float* __restrict__ sp, float* __restrict__ sq) {
    int t = blockIdx.x * 256 + threadIdx.x;
    if (t >= LJ / 8) return;   // 900
    int c = blockIdx.y;
    const u16x8* base = (const u16x8*)(A16 + (long)c * BPC * LJ) + t;
    float s[8], q[8];
    #pragma unroll
    for (int i = 0; i < 8; ++i) { s[i] = 0.f; q[i] = 0.f; }
    #pragma unroll 4
    for (int b = 0; b < BPC; ++b) {
        u16x8 v = base[(long)b * (LJ / 8)];
        #pragma unroll
        for (int i = 0; i < 8; ++i) {
            float f = bf2f(v[i]);
            s[i] += f; q[i] += f * f;
        }
    }
    #pragma unroll
    for (int i = 0; i < 8; ++i) {
        sp[(long)c * LJ + t * 8 + i] = s[i];
        sq[(long)c * LJ + t * 8 + i] = q[i];
    }
}

// K1c: finish stats -> packed bf16 {mean, rstd} per lj
__global__ void k_stats_fin(const float* __restrict__ sp, const float* __restrict__ sq,
                            unsigned* __restrict__ mr16) {
    int lj = blockIdx.x * 256 + threadIdx.x;
    if (lj >= LJ) return;
    float s = 0.f, q = 0.f;
    for (int c = 0; c < BCH; ++c) { s += sp[(long)c * LJ + lj]; q += sq[(long)c * LJ + lj]; }
    float m = s * (1.0f / B_);
    float v = fmaxf(q * (1.0f / B_) - m * m, 0.f);
    mr16[lj] = cvtpk(m, rsqrtf(v + EPS_));   // lo = mean, hi = rstd
}

// K2a: w[row] = dice(A[row]) · auW2 + b2 — A16 LDS-staged
__global__ __launch_bounds__(256) void k_w(const unsigned short* __restrict__ A16,
        const unsigned* __restrict__ mr16, const float* __restrict__ c01,
        const float* __restrict__ aub2, float* __restrict__ wbuf) {
    __shared__ __align__(16) unsigned short aL[256 * NJ];   // 18 KB
    int tid = threadIdx.x;
    const u16x8* gsrc = (const u16x8*)(A16 + (long)blockIdx.x * 256 * NJ);
    u16x8* ld = (u16x8*)aL;
    #pragma unroll
    for (int i = 0; i < 4; ++i) ld[i * 256 + tid] = gsrc[i * 256 + tid];
    if (tid < 128) ld[1024 + tid] = gsrc[1024 + tid];
    __syncthreads();

    int row = blockIdx.x * 256 + tid;
    int l = row % L_;
    const u16x4* Ab4 = (const u16x4*)(aL + tid * NJ);
    const u16x8* mrp = (const u16x8*)(mr16 + l * NJ);
    float w = aub2[0];
    #pragma unroll
    for (int cgi = 0; cgi < 9; ++cgi) {
        u16x4 av = Ab4[cgi];
        u16x8 mr = mrp[cgi];
        #pragma unroll
        for (int i = 0; i < 4; ++i) {
            int j = cgi * 4 + i;
            float s = bf2f(av[i]);
            float p = sigmoidf_((s - bf2f(mr[2 * i])) * bf2f(mr[2 * i + 1]));
            w += s * fmaf(c01[2 * j + 1], p, c01[2 * j]);
        }
    }
    wbuf[row] = w;
}

// K2b: cur[b][d] = sum_l w[b][l] * h[b][l][d]; z = [u|it|c|cur]
__global__ __launch_bounds__(256) void k_pool(const int* __restrict__ histT,
        const int* __restrict__ user, const int* __restrict__ item, const int* __restrict__ cate,
        const float* __restrict__ u_emb, const float* __restrict__ i_emb, const float* __restrict__ c_emb,
        const unsigned short* __restrict__ i_emb16, const float* __restrict__ wbuf,
        float* __restrict__ z_buf) {
    __shared__ float part[4][D_];
    int b = blockIdx.x;
    int tid = threadIdx.x;
    int q = tid >> 6, d = tid & 63;
    const int* rp = histT + b * L_;       // wave-uniform -> s_load
    const float* wp = wbuf + (long)b * L_;
    float s = 0.f;
    int l0 = q * 50;
    #pragma unroll 5
    for (int i = 0; i < 50; ++i) {
        int ll = l0 + i;
        s += wp[ll] * bf2f(i_emb16[(long)rp[ll] * D_ + d]);
    }
    part[q][d] = s;
    __syncthreads();
    if (q == 0) {
        z_buf[b * 256 + 192 + d] = part[0][d] + part[1][d] + part[2][d] + part[3][d];
    } else if (q == 1) {
        z_buf[b * 256 + d]       = u_emb[(long)user[b] * D_ + d];
    } else if (q == 2) {
        z_buf[b * 256 + 64 + d]  = i_emb[(long)item[b] * D_ + d];
    } else {
        z_buf[b * 256 + 128 + d] = c_emb[(long)cate[b] * D_ + d];
    }
}

// K4: y1 = z @ W1 + b1 (+ batch stats)
__global__ __launch_bounds__(256) void k_mlp1(const float* __restrict__ z_buf,
        const float* __restrict__ W1, const float* __restrict__ b1,
        float* __restrict__ y1, float* __restrict__ gs1, float* __restrict__ gq1) {
    __shared__ float zt[16 * 256];
    __shared__ float w_s[256 * H1];
    __shared__ float ls[H1], lq[H1];
    int tid = threadIdx.x;
    int b0 = blockIdx.x * 16;
    for (int i = tid; i < 16 * 256; i += 256) zt[i] = z_buf[b0 * 256 + i];
    for (int i = tid; i < 256 * H1; i += 256) w_s[i] = W1[i];
    if (tid < H1) { ls[tid] = 0.f; lq[tid] = 0.f; }
    __syncthreads();
    for (int o = tid; o < 16 * H1; o += 256) {
        int bl = o / H1, j = o - bl * H1;
        float s = b1[j];
        for (int k = 0; k < 256; ++k) s += zt[bl * 256 + k] * w_s[k * H1 + j];
        y1[(b0 + bl) * H1 + j] = s;
        atomicAdd(&ls[j], s); atomicAdd(&lq[j], s * s);
    }
    __syncthreads();
    if (tid < H1) { atomicAdd(&gs1[tid], ls[tid]); atomicAdd(&gq1[tid], lq[tid]); }
}

// K6: a1 = dice1(y1); y2 = a1 @ W2 + b2 (+ stats). m1/r1 computed per-block from gs1/gq1
__global__ __launch_bounds__(256) void k_mlp2(const float* __restrict__ y1,
        const float* __restrict__ gs1, const float* __restrict__ gq1, const float* __restrict__ alpha1,
        const float* __restrict__ W2, const float* __restrict__ b2,
        float* __restrict__ y2, float* __restrict__ gs2, float* __restrict__ gq2) {
    __shared__ float at[16 * H1];
    __shared__ float w_s[H1 * H2];
    __shared__ float ls[H2], lq[H2];
    __shared__ float m1s[H1], r1s[H1];
    int tid = threadIdx.x;
    int b0 = blockIdx.x * 16;
    if (tid < H1) {
        float mm = gs1[tid] * (1.0f / B_);
        float v = fmaxf(gq1[tid] * (1.0f / B_) - mm * mm, 0.f);
        m1s[tid] = mm; r1s[tid] = rsqrtf(v + EPS_);
    }
    for (int i = tid; i < H1 * H2; i += 256) w_s[i] = W2[i];
    if (tid < H2) { ls[tid] = 0.f; lq[tid] = 0.f; }
    __syncthreads();
    for (int i = tid; i < 16 * H1; i += 256) {
        float x = y1[b0 * H1 + i];
        int j = i % H1;
        float p = sigmoidf_((x - m1s[j]) * r1s[j]);
        at[i] = x * (p + alpha1[j] * (1.f - p));
    }
    __syncthreads();
    for (int o = tid; o < 16 * H2; o += 256) {
        int bl = o / H2, j = o - bl * H2;
        float s = b2[j];
        #pragma unroll
        for (int k = 0; k < H1; ++k) s += at[bl * H1 + k] * w_s[k * H2 + j];
        y2[(b0 + bl) * H2 + j] = s;
        atomicAdd(&ls[j], s); atomicAdd(&lq[j], s * s);
    }
    __syncthreads();
    if (tid < H2) { atomicAdd(&gs2[tid], ls[tid]); atomicAdd(&gq2[tid], lq[tid]); }
}

// K8: out = dice2(y2) @ W3 + b3. m2/r2 computed per-block from gs2/gq2
__global__ __launch_bounds__(256) void k_out(const float* __restrict__ y2,
        const float* __restrict__ gs2, const float* __restrict__ gq2, const float* __restrict__ alpha2,
        const float* __restrict__ W3, const float* __restrict__ b3, float* __restrict__ out) {
    __shared__ float m2s[H2], r2s[H2];
    int tid = threadIdx.x;
    if (tid < H2) {
        float mm = gs2[tid] * (1.0f / B_);
        float v = fmaxf(gq2[tid] * (1.0f / B_) - mm * mm, 0.f);
        m2s[tid] = mm; r2s[tid] = rsqrtf(v + EPS_);
    }
    __syncthreads();
    int b = blockIdx.x * 256 + tid;
    if (b >= B_) return;
    float s0 = b3[0], s1 = b3[1];
    #pragma unroll
    for (int k = 0; k < H2; ++k) {
        float x = y2[b * H2 + k];
        float p = sigmoidf_((x - m2s[k]) * r2s[k]);
        float a = x * (p + alpha2[k] * (1.f - p));
        s0 += a * W3[k * 2];
        s1 += a * W3[k * 2 + 1];
    }
    out[b * 2] = s0;
    out[b * 2 + 1] = s1;
}

extern "C" void kernel_launch(void* const* d_in, const int* in_sizes, int n_in,
                              void* d_out, int out_size, void* d_ws, size_t ws_size,
                              hipStream_t stream) {
    const int*   user  = (const int*)d_in[0];
    const int*   hist  = (const int*)d_in[1];
    const int*   item  = (const int*)d_in[2];
    const int*   cate  = (const int*)d_in[3];
    const float* u_emb = (const float*)d_in[4];
    const float* i_emb = (const float*)d_in[5];
    const float* c_emb = (const float*)d_in[6];
    const float* auW1  = (const float*)d_in[7];
    const float* aub1  = (const float*)d_in[8];
    const float* aual  = (const float*)d_in[9];
    const float* auW2  = (const float*)d_in[10];
    const float* aub2  = (const float*)d_in[11];
    const float* W1    = (const float*)d_in[12];
    const float* b1    = (const float*)d_in[13];
    const float* al1   = (const float*)d_in[14];
    const float* W2    = (const float*)d_in[15];
    const float* b2    = (const float*)d_in[16];
    const float* al2   = (const float*)d_in[17];
    const float* W3    = (const float*)d_in[18];
    const float* b3    = (const float*)d_in[19];

    unsigned short* A16    = (unsigned short*)d_ws;            // 59 MB bf16
    unsigned short* wfrag  = A16 + (size_t)NROW * NJ;          // 13.8 KB
    unsigned short* iemb16 = wfrag + WF_SZ;                    // 12.8 MB
    float* ws = (float*)(iemb16 + (size_t)NITEM * D_);
    size_t off = 0;
    float* sp    = ws + off; off += (size_t)BCH * LJ;          // 3.7 MB
    float* sq    = ws + off; off += (size_t)BCH * LJ;          // 3.7 MB
    unsigned* mr16 = (unsigned*)(ws + off); off += LJ;         // 28.8 KB packed {m,r}
    float* c01   = ws + off; off += 2 * NJ;
    float* gs1   = ws + off; off += H1;
    float* gq1   = ws + off; off += H1;
    float* gs2   = ws + off; off += H2;
    float* gq2   = ws + off; off += H2;
    float* z_buf = ws + off; off += (size_t)B_ * 256;
    float* y1    = ws + off; off += (size_t)B_ * H1;
    float* y2    = ws + off; off += (size_t)B_ * H2;
    float* wbuf  = ws + off; off += NROW;                      // 3.3 MB
    int* histT   = (int*)(ws + off); off += NROW;              // 3.3 MB

    k_pre<<<NPRE, 256, 0, stream>>>(i_emb, iemb16, hist, histT, auW1, wfrag,
                                    aual, auW2, c01, gs1);
    k_gemm<<<NGRID2, 256, 0, stream>>>(histT, item, iemb16, wfrag, aub1, A16);
    {
        dim3 g(4, BCH);
        k_stats_p<<<g, 256, 0, stream>>>(A16, sp, sq);
    }
    k_stats_fin<<<(LJ + 255) / 256, 256, 0, stream>>>(sp, sq, mr16);
    k_w<<<NROW / 256, 256, 0, stream>>>(A16, mr16, c01, aub2, wbuf);
    k_pool<<<B_, 256, 0, stream>>>(histT, user, item, cate, u_emb, i_emb, c_emb,
                                   iemb16, wbuf, z_buf);
    k_mlp1<<<B_ / 16, 256, 0, stream>>>(z_buf, W1, b1, y1, gs1, gq1);
    k_mlp2<<<B_ / 16, 256, 0, stream>>>(y1, gs1, gq1, al1, W2, b2, y2, gs2, gq2);
    k_out<<<B_ / 256, 256, 0, stream>>>(y2, gs2, gq2, al2, W3, b3, (float*)d_out);
}